// Round 1
// baseline (6328.234 us; speedup 1.0000x reference)
//
#include <hip/hip_runtime.h>
#include <math.h>

#define N_NODES 50000
#define N_EDGES 800000
#define TPB 256

// ---------------- fused GEMM: out = act(A1'@W1 [+ A2@W2] + b) ----------------
// A1' = A1 row-scaled by 1/max(cnt,1) when cnt != nullptr (SAGE mean).
// 16 rows of A staged in LDS per block; one column per thread.
// LDS reads are wave-uniform (broadcast, conflict-free); W reads coalesced.
template<int ACT, bool HAS2>
__global__ void mm_fused(const float* __restrict__ A1, const float* __restrict__ W1,
                         const float* __restrict__ A2, const float* __restrict__ W2,
                         const float* __restrict__ bias, const float* __restrict__ cnt,
                         float* __restrict__ out, int K, int NO) {
    extern __shared__ float sm[];
    float* s1 = sm;             // 16*K
    float* s2 = sm + 16 * K;    // 16*K (iff HAS2)
    const int r0 = blockIdx.x * 16;
    const int tid = threadIdx.x;

    for (int idx = tid; idx < 16 * K; idx += TPB) {
        int r = idx / K, k = idx - r * K;
        int n = r0 + r;
        float v1 = 0.f, v2 = 0.f;
        if (n < N_NODES) {
            v1 = A1[(size_t)n * K + k];
            if (cnt) v1 *= 1.0f / fmaxf(cnt[n], 1.0f);
            if (HAS2) v2 = A2[(size_t)n * K + k];
        }
        s1[idx] = v1;
        if (HAS2) s2[idx] = v2;
    }
    __syncthreads();

    for (int col = tid; col < NO; col += TPB) {
        float acc[16];
#pragma unroll
        for (int r = 0; r < 16; ++r) acc[r] = 0.f;
        for (int k = 0; k < K; ++k) {
            float w1 = W1[k * NO + col];
            float w2 = HAS2 ? W2[k * NO + col] : 0.f;
#pragma unroll
            for (int r = 0; r < 16; ++r) {
                acc[r] = fmaf(s1[r * K + k], w1, acc[r]);
                if (HAS2) acc[r] = fmaf(s2[r * K + k], w2, acc[r]);
            }
        }
        float bb = bias ? bias[col] : 0.f;
#pragma unroll
        for (int r = 0; r < 16; ++r) {
            int n = r0 + r;
            if (n < N_NODES) {
                float v = acc[r] + bb;
                if (ACT == 1) v = fmaxf(v, 0.f);
                out[(size_t)n * NO + col] = v;
            }
        }
    }
}

// ---------------- graph primitives ----------------
__global__ void count_k(const int* __restrict__ dst, float* __restrict__ cnt) {
    int e = blockIdx.x * TPB + threadIdx.x;
    if (e < N_EDGES) atomicAdd(&cnt[dst[e]], 1.0f);
}

__global__ void scatter_add(const int* __restrict__ src, const int* __restrict__ dst,
                            const float* __restrict__ feat, float* __restrict__ agg, int F) {
    int idx = blockIdx.x * TPB + threadIdx.x;
    int total = N_EDGES * F;   // max 102.4M < 2^31
    if (idx >= total) return;
    int e = idx / F, c = idx - e * F;
    atomicAdd(&agg[(size_t)dst[e] * F + c], feat[(size_t)src[e] * F + c]);
}

// per-(node,head) attention scores: a_s / a_d
__global__ void att_scores(const float* __restrict__ h, const float* __restrict__ att_src,
                           const float* __restrict__ att_dst, float* __restrict__ as_,
                           float* __restrict__ ad_) {
    int idx = blockIdx.x * TPB + threadIdx.x;
    if (idx >= N_NODES * 4) return;
    int n = idx >> 2, hd = idx & 3;
    const float* row = h + (size_t)n * 128 + hd * 32;
    float sa = 0.f, sd = 0.f;
    for (int c = 0; c < 32; ++c) {
        float v = row[c];
        sa = fmaf(v, att_src[hd * 32 + c], sa);
        sd = fmaf(v, att_dst[hd * 32 + c], sd);
    }
    as_[idx] = sa;
    ad_[idx] = sd;
}

__device__ __forceinline__ float leaky02(float a) { return a >= 0.f ? a : 0.2f * a; }

// segment max of e over dst, via order-preserving uint encoding + atomicMax
__global__ void gat_max_k(const int* __restrict__ src, const int* __restrict__ dst,
                          const float* __restrict__ as_, const float* __restrict__ ad_,
                          unsigned* __restrict__ m_) {
    int idx = blockIdx.x * TPB + threadIdx.x;
    if (idx >= N_EDGES * 4) return;
    int e = idx >> 2, hd = idx & 3;
    float a = leaky02(as_[src[e] * 4 + hd] + ad_[dst[e] * 4 + hd]);
    unsigned b = __float_as_uint(a);
    unsigned enc = (b >> 31) ? ~b : (b | 0x80000000u);
    atomicMax(&m_[dst[e] * 4 + hd], enc);
}

// accumulate s = sum(ex) and out += h[src]*ex (normalize later)
__global__ void gat_accum_k(const int* __restrict__ src, const int* __restrict__ dst,
                            const float* __restrict__ as_, const float* __restrict__ ad_,
                            const unsigned* __restrict__ m_, float* __restrict__ s_,
                            const float* __restrict__ h, float* __restrict__ outD) {
    int idx = blockIdx.x * TPB + threadIdx.x;
    if (idx >= N_EDGES * 4) return;
    int e = idx >> 2, hd = idx & 3;
    int ss = src[e], dd = dst[e];
    float a = leaky02(as_[ss * 4 + hd] + ad_[dd * 4 + hd]);
    unsigned mu = m_[dd * 4 + hd];
    unsigned mb = (mu >> 31) ? (mu ^ 0x80000000u) : ~mu;
    float ex = __expf(a - __uint_as_float(mb));
    atomicAdd(&s_[dd * 4 + hd], ex);
    const float* hrow = h + (size_t)ss * 128 + hd * 32;
    float* orow = outD + (size_t)dd * 128 + hd * 32;
#pragma unroll 4
    for (int c = 0; c < 32; ++c) atomicAdd(&orow[c], hrow[c] * ex);
}

// out = elu(out / (s + 1e-16) + bias)   (in place)
__global__ void gat_final_k(float* __restrict__ D, const float* __restrict__ s_,
                            const float* __restrict__ gb) {
    int idx = blockIdx.x * TPB + threadIdx.x;
    if (idx >= N_NODES * 128) return;
    int n = idx >> 7, c = idx & 127, hd = c >> 5;
    float v = D[idx] / (s_[n * 4 + hd] + 1e-16f) + gb[c];
    D[idx] = v > 0.f ? v : expm1f(v);
}

// classifier: [N,256] @ [256,5] + b
__global__ void cls_k(const float* __restrict__ h, const float* __restrict__ W,
                      const float* __restrict__ b, float* __restrict__ out) {
    __shared__ float sW[256 * 5];
    for (int i = threadIdx.x; i < 1280; i += TPB) sW[i] = W[i];
    __syncthreads();
    int n = blockIdx.x * TPB + threadIdx.x;
    if (n >= N_NODES) return;
    const float4* row = (const float4*)(h + (size_t)n * 256);
    float acc[5] = {0.f, 0.f, 0.f, 0.f, 0.f};
    for (int k4 = 0; k4 < 64; ++k4) {
        float4 v = row[k4];
        const float* w = &sW[k4 * 4 * 5];
#pragma unroll
        for (int c = 0; c < 5; ++c) acc[c] = fmaf(v.x, w[c], acc[c]);
#pragma unroll
        for (int c = 0; c < 5; ++c) acc[c] = fmaf(v.y, w[5 + c], acc[c]);
#pragma unroll
        for (int c = 0; c < 5; ++c) acc[c] = fmaf(v.z, w[10 + c], acc[c]);
#pragma unroll
        for (int c = 0; c < 5; ++c) acc[c] = fmaf(v.w, w[15 + c], acc[c]);
    }
#pragma unroll
    for (int c = 0; c < 5; ++c) out[(size_t)n * 5 + c] = acc[c] + b[c];
}

extern "C" void kernel_launch(void* const* d_in, const int* in_sizes, int n_in,
                              void* d_out, int out_size, void* d_ws, size_t ws_size,
                              hipStream_t stream) {
    const float* x    = (const float*)d_in[0];
    const int*   ei   = (const int*)d_in[1];
    const float* s1Wl = (const float*)d_in[2];
    const float* s1Wr = (const float*)d_in[3];
    const float* s1b  = (const float*)d_in[4];
    const float* gW   = (const float*)d_in[5];
    const float* gas  = (const float*)d_in[6];
    const float* gad  = (const float*)d_in[7];
    const float* gb   = (const float*)d_in[8];
    const float* s2Wl = (const float*)d_in[9];
    const float* s2Wr = (const float*)d_in[10];
    const float* s2b  = (const float*)d_in[11];
    const float* clsW = (const float*)d_in[12];
    const float* clsb = (const float*)d_in[13];
    float* out = (float*)d_out;
    const int* src = ei;            // edge_index[0]
    const int* dst = ei + N_EDGES;  // edge_index[1]

    float* ws  = (float*)d_ws;
    float* cnt = ws;                                  // N
    float* A   = cnt + N_NODES;                       // N*256 (h1, then h3)
    float* B   = A + (size_t)N_NODES * 256;           // N*128 (agg)
    float* C   = B + (size_t)N_NODES * 128;           // N*128 (gat h)
    float* D   = C + (size_t)N_NODES * 128;           // N*128 (gat out / h2)
    float* as_ = D + (size_t)N_NODES * 128;           // N*4
    float* ad_ = as_ + N_NODES * 4;                   // N*4
    unsigned* m_ = (unsigned*)(ad_ + N_NODES * 4);    // N*4 (encoded max; 0 == -NaN, only read for dsts with edges)
    float* s_  = (float*)(m_ + N_NODES * 4);          // N*4

    hipMemsetAsync(cnt, 0, N_NODES * sizeof(float), stream);
    hipMemsetAsync(B, 0, (size_t)N_NODES * 20 * sizeof(float), stream);
    hipMemsetAsync(D, 0, (size_t)N_NODES * 128 * sizeof(float), stream);
    hipMemsetAsync(m_, 0, N_NODES * 4 * sizeof(unsigned), stream);
    hipMemsetAsync(s_, 0, N_NODES * 4 * sizeof(float), stream);

    // degree counts (shared by both SAGE layers)
    count_k<<<(N_EDGES + TPB - 1) / TPB, TPB, 0, stream>>>(dst, cnt);

    // ---- SAGE1 ----
    scatter_add<<<(N_EDGES * 20 + TPB - 1) / TPB, TPB, 0, stream>>>(src, dst, x, B, 20);
    mm_fused<1, true><<<N_NODES / 16, TPB, 2 * 16 * 20 * sizeof(float), stream>>>(
        B, s1Wl, x, s1Wr, s1b, cnt, A, 20, 256);

    // ---- GAT ----
    mm_fused<0, false><<<N_NODES / 16, TPB, 16 * 256 * sizeof(float), stream>>>(
        A, gW, nullptr, nullptr, nullptr, nullptr, C, 256, 128);
    att_scores<<<(N_NODES * 4 + TPB - 1) / TPB, TPB, 0, stream>>>(C, gas, gad, as_, ad_);
    gat_max_k<<<(N_EDGES * 4 + TPB - 1) / TPB, TPB, 0, stream>>>(src, dst, as_, ad_, m_);
    gat_accum_k<<<(N_EDGES * 4 + TPB - 1) / TPB, TPB, 0, stream>>>(src, dst, as_, ad_, m_, s_, C, D);
    gat_final_k<<<(N_NODES * 128 + TPB - 1) / TPB, TPB, 0, stream>>>(D, s_, gb);

    // ---- SAGE2 ----
    hipMemsetAsync(B, 0, (size_t)N_NODES * 128 * sizeof(float), stream);
    scatter_add<<<(N_EDGES * 128 + TPB - 1) / TPB, TPB, 0, stream>>>(src, dst, D, B, 128);
    mm_fused<1, true><<<N_NODES / 16, TPB, 2 * 16 * 128 * sizeof(float), stream>>>(
        B, s2Wl, D, s2Wr, s2b, cnt, A, 128, 256);

    // ---- classifier ----
    cls_k<<<(N_NODES + TPB - 1) / TPB, TPB, 0, stream>>>(A, clsW, clsb, out);
}

// Round 3
// 847.420 us; speedup vs baseline: 7.4676x; 7.4676x over previous
//
#include <hip/hip_runtime.h>
#include <math.h>

#define N_NODES 50000
#define N_EDGES 800000
#define TPB 256

// ---------------- fused GEMM: out = act(A1@W1 [+ A2@W2] + b) ----------------
// 16 rows of A staged in LDS per block; one column per thread.
// LDS reads are wave-uniform (broadcast, conflict-free); W reads coalesced.
template<int ACT, bool HAS2>
__global__ void mm_fused(const float* __restrict__ A1, const float* __restrict__ W1,
                         const float* __restrict__ A2, const float* __restrict__ W2,
                         const float* __restrict__ bias,
                         float* __restrict__ out, int K, int NO) {
    extern __shared__ float sm[];
    float* s1 = sm;             // 16*K
    float* s2 = sm + 16 * K;    // 16*K (iff HAS2)
    const int r0 = blockIdx.x * 16;
    const int tid = threadIdx.x;

    for (int idx = tid; idx < 16 * K; idx += TPB) {
        int r = idx / K, k = idx - r * K;
        int n = r0 + r;
        float v1 = 0.f, v2 = 0.f;
        if (n < N_NODES) {
            v1 = A1[(size_t)n * K + k];
            if (HAS2) v2 = A2[(size_t)n * K + k];
        }
        s1[idx] = v1;
        if (HAS2) s2[idx] = v2;
    }
    __syncthreads();

    for (int col = tid; col < NO; col += TPB) {
        float acc[16];
#pragma unroll
        for (int r = 0; r < 16; ++r) acc[r] = 0.f;
        for (int k = 0; k < K; ++k) {
            float w1 = W1[k * NO + col];
            float w2 = HAS2 ? W2[k * NO + col] : 0.f;
#pragma unroll
            for (int r = 0; r < 16; ++r) {
                acc[r] = fmaf(s1[r * K + k], w1, acc[r]);
                if (HAS2) acc[r] = fmaf(s2[r * K + k], w2, acc[r]);
            }
        }
        float bb = bias ? bias[col] : 0.f;
#pragma unroll
        for (int r = 0; r < 16; ++r) {
            int n = r0 + r;
            if (n < N_NODES) {
                float v = acc[r] + bb;
                if (ACT == 1) v = fmaxf(v, 0.f);
                out[(size_t)n * NO + col] = v;
            }
        }
    }
}

// ---------------- CSR construction ----------------
__global__ void hist_k(const int* __restrict__ dst, int* __restrict__ deg) {
    int e = blockIdx.x * TPB + threadIdx.x;
    if (e < N_EDGES) atomicAdd(&deg[dst[e]], 1);
}

// single-block exclusive scan over deg -> rowptr (N_NODES+1 entries)
__global__ void scan_k(const int* __restrict__ deg, int* __restrict__ rowptr) {
    __shared__ int part[1024];
    const int tid = threadIdx.x;                     // 1024 threads
    const int CH = (N_NODES + 1023) / 1024;          // 49
    const int base = tid * CH;
    int s = 0;
    for (int i = 0; i < CH; ++i) {
        int idx = base + i;
        if (idx < N_NODES) s += deg[idx];
    }
    part[tid] = s;
    __syncthreads();
    for (int off = 1; off < 1024; off <<= 1) {
        int v = (tid >= off) ? part[tid - off] : 0;
        __syncthreads();
        part[tid] += v;
        __syncthreads();
    }
    int run = (tid == 0) ? 0 : part[tid - 1];
    for (int i = 0; i < CH; ++i) {
        int idx = base + i;
        if (idx < N_NODES) {
            rowptr[idx] = run;
            run += deg[idx];
        }
    }
    if (tid == 1023) rowptr[N_NODES] = run;
}

__global__ void fill_k(const int* __restrict__ src, const int* __restrict__ dst,
                       const int* __restrict__ rowptr, int* __restrict__ fill,
                       int* __restrict__ csr_src) {
    int e = blockIdx.x * TPB + threadIdx.x;
    if (e >= N_EDGES) return;
    int d = dst[e];
    int pos = rowptr[d] + atomicAdd(&fill[d], 1);
    csr_src[pos] = src[e];
}

// ---------------- gather aggregations (no scatter atomics) ----------------
template<int F, int BLK>
__global__ void gather_mean(const int* __restrict__ rowptr, const int* __restrict__ csr_src,
                            const float* __restrict__ feat, float* __restrict__ out) {
    int n = blockIdx.x;
    int c = threadIdx.x;
    if (c >= F) return;
    int e0 = rowptr[n], e1 = rowptr[n + 1];
    float acc = 0.f;
    for (int e = e0; e < e1; ++e)
        acc += feat[(size_t)csr_src[e] * F + c];
    out[(size_t)n * F + c] = acc / fmaxf((float)(e1 - e0), 1.0f);
}

// per-(node,head) attention scores
__global__ void att_scores(const float* __restrict__ h, const float* __restrict__ att_src,
                           const float* __restrict__ att_dst, float* __restrict__ as_,
                           float* __restrict__ ad_) {
    int idx = blockIdx.x * TPB + threadIdx.x;
    if (idx >= N_NODES * 4) return;
    int n = idx >> 2, hd = idx & 3;
    const float* row = h + (size_t)n * 128 + hd * 32;
    float sa = 0.f, sd = 0.f;
    for (int c = 0; c < 32; ++c) {
        float v = row[c];
        sa = fmaf(v, att_src[hd * 32 + c], sa);
        sd = fmaf(v, att_dst[hd * 32 + c], sd);
    }
    as_[idx] = sa;
    ad_[idx] = sd;
}

// fused GAT aggregation: online softmax per thread + weighted gather + ELU
__global__ void gat_gather(const int* __restrict__ rowptr, const int* __restrict__ csr_src,
                           const float* __restrict__ h, const float* __restrict__ as_,
                           const float* __restrict__ ad_, const float* __restrict__ gb,
                           float* __restrict__ out) {
    int n = blockIdx.x;
    int c = threadIdx.x;           // 0..127
    int hd = c >> 5;
    int e0 = rowptr[n], e1 = rowptr[n + 1];
    float ad = ad_[n * 4 + hd];
    float m = -INFINITY, s = 0.f, acc = 0.f;
    for (int e = e0; e < e1; ++e) {
        int sn = csr_src[e];
        float a = as_[sn * 4 + hd] + ad;
        a = a >= 0.f ? a : 0.2f * a;              // leaky_relu 0.2
        if (a > m) {                               // online softmax rescale
            float sc = __expf(m - a);
            s *= sc; acc *= sc; m = a;
        }
        float ex = __expf(a - m);
        s += ex;
        acc = fmaf(h[(size_t)sn * 128 + c], ex, acc);
    }
    float v = acc / (s + 1e-16f) + gb[c];
    out[(size_t)n * 128 + c] = v > 0.f ? v : expm1f(v);
}

// classifier: [N,256] @ [256,5] + b
__global__ void cls_k(const float* __restrict__ h, const float* __restrict__ W,
                      const float* __restrict__ b, float* __restrict__ out) {
    __shared__ float sW[256 * 5];
    for (int i = threadIdx.x; i < 1280; i += TPB) sW[i] = W[i];
    __syncthreads();
    int n = blockIdx.x * TPB + threadIdx.x;
    if (n >= N_NODES) return;
    const float4* row = (const float4*)(h + (size_t)n * 256);
    float acc[5] = {0.f, 0.f, 0.f, 0.f, 0.f};
    for (int k4 = 0; k4 < 64; ++k4) {
        float4 v = row[k4];
        const float* w = &sW[k4 * 4 * 5];
#pragma unroll
        for (int c = 0; c < 5; ++c) acc[c] = fmaf(v.x, w[c], acc[c]);
#pragma unroll
        for (int c = 0; c < 5; ++c) acc[c] = fmaf(v.y, w[5 + c], acc[c]);
#pragma unroll
        for (int c = 0; c < 5; ++c) acc[c] = fmaf(v.z, w[10 + c], acc[c]);
#pragma unroll
        for (int c = 0; c < 5; ++c) acc[c] = fmaf(v.w, w[15 + c], acc[c]);
    }
#pragma unroll
    for (int c = 0; c < 5; ++c) out[(size_t)n * 5 + c] = acc[c] + b[c];
}

extern "C" void kernel_launch(void* const* d_in, const int* in_sizes, int n_in,
                              void* d_out, int out_size, void* d_ws, size_t ws_size,
                              hipStream_t stream) {
    const float* x    = (const float*)d_in[0];
    const int*   ei   = (const int*)d_in[1];
    const float* s1Wl = (const float*)d_in[2];
    const float* s1Wr = (const float*)d_in[3];
    const float* s1b  = (const float*)d_in[4];
    const float* gW   = (const float*)d_in[5];
    const float* gas  = (const float*)d_in[6];
    const float* gad  = (const float*)d_in[7];
    const float* gb   = (const float*)d_in[8];
    const float* s2Wl = (const float*)d_in[9];
    const float* s2Wr = (const float*)d_in[10];
    const float* s2b  = (const float*)d_in[11];
    const float* clsW = (const float*)d_in[12];
    const float* clsb = (const float*)d_in[13];
    float* out = (float*)d_out;
    const int* src = ei;            // edge_index[0]
    const int* dst = ei + N_EDGES;  // edge_index[1]

    // ---- workspace layout (all fully rewritten each call; no stale reads) ----
    float* ws  = (float*)d_ws;
    float* A   = ws;                                  // N*256 (h1, then h3)
    float* C   = A + (size_t)N_NODES * 256;           // N*128 (gat h; later sage2 mean)
    float* D   = C + (size_t)N_NODES * 128;           // N*128 (sage1 mean(20); later gat out/h2)
    float* as_ = D + (size_t)N_NODES * 128;           // N*4
    float* ad_ = as_ + N_NODES * 4;                   // N*4
    int* deg     = (int*)(ad_ + N_NODES * 4);         // N
    int* fill    = deg + N_NODES;                     // N
    int* rowptr  = fill + N_NODES;                    // N+1
    int* csr_src = rowptr + N_NODES + 1;              // E

    // ---- CSR build ----
    hipMemsetAsync(deg, 0, N_NODES * sizeof(int), stream);
    hipMemsetAsync(fill, 0, N_NODES * sizeof(int), stream);
    hist_k<<<(N_EDGES + TPB - 1) / TPB, TPB, 0, stream>>>(dst, deg);
    scan_k<<<1, 1024, 0, stream>>>(deg, rowptr);
    fill_k<<<(N_EDGES + TPB - 1) / TPB, TPB, 0, stream>>>(src, dst, rowptr, fill, csr_src);

    // ---- SAGE1 ----
    gather_mean<20, 64><<<N_NODES, 64, 0, stream>>>(rowptr, csr_src, x, D);
    mm_fused<1, true><<<N_NODES / 16, TPB, 2 * 16 * 20 * sizeof(float), stream>>>(
        D, s1Wl, x, s1Wr, s1b, A, 20, 256);

    // ---- GAT ----
    mm_fused<0, false><<<N_NODES / 16, TPB, 16 * 256 * sizeof(float), stream>>>(
        A, gW, nullptr, nullptr, nullptr, C, 256, 128);
    att_scores<<<(N_NODES * 4 + TPB - 1) / TPB, TPB, 0, stream>>>(C, gas, gad, as_, ad_);
    gat_gather<<<N_NODES, 128, 0, stream>>>(rowptr, csr_src, C, as_, ad_, gb, D);

    // ---- SAGE2 ----
    gather_mean<128, 128><<<N_NODES, 128, 0, stream>>>(rowptr, csr_src, D, C);
    mm_fused<1, true><<<N_NODES / 16, TPB, 2 * 16 * 128 * sizeof(float), stream>>>(
        C, s2Wl, D, s2Wr, s2b, A, 128, 256);

    // ---- classifier ----
    cls_k<<<(N_NODES + TPB - 1) / TPB, TPB, 0, stream>>>(A, clsW, clsb, out);
}